// Round 2
// baseline (60.960 us; speedup 1.0000x reference)
//
#include <hip/hip_runtime.h>
#include <math.h>

// Heisenberg-picture closed form. Conjugating each measured Z_w backward
// through the circuit (RX t0 q0 | RY t1 q1 | RZ t2 q2 | CNOT 0->2 | RX t3 q3 |
// RY t4 q0 | CNOT 1->3 | RZ t5 q2) and taking the expectation under the real
// product state (per-qubit <X>=sin a, <Y>=0, <Z>=cos a) gives:
//   m0 = c0*c4*cos(a0) - c2*s4*sin(a0)*sin(a2)
//   m1 = cos(a1 + t1)
//   m2 = c0*cos(a0)*cos(a2)
//   m3 = c3*cos(a1 + t1)*cos(a3)
// with c_k = cos(t_k), s_k = sin(t_k) (FULL gate angles). t5 drops out.
//
// V2b: two adjacent patches per thread.
//  - loads become global_load_dwordx4 (16 B/lane, coalescing sweet spot)
//    instead of 2x dwordx2 (8 B/lane),
//  - 2x the independent work per wave to hide HBM latency (input is cold
//    every iteration: the harness's 256 MiB poison fill evicts L2+L3),
//  - output stores are non-temporal via clang native vector type
//    (__builtin_nontemporal_store rejects HIP_vector_type structs).
// 262144 threads = 4096 waves = 4 waves/SIMD over 1024 SIMDs.

typedef float vf4 __attribute__((ext_vector_type(4)));

__global__ __launch_bounds__(256) void qfe_kernel(
    const float* __restrict__ x, const float* __restrict__ tp,
    float* __restrict__ out, int M)
{
    int m = blockIdx.x * blockDim.x + threadIdx.x;  // m indexes a PAIR of patches
    if (m >= M) return;

    // Wave-uniform gate trig (tp address is uniform -> scalar loads).
    float c0 = __cosf(tp[0]);
    float s1, c1; __sincosf(tp[1], &s1, &c1);
    float c2 = __cosf(tp[2]);
    float c3 = __cosf(tp[3]);
    float s4, c4; __sincosf(tp[4], &s4, &c4);
    float k00 = c0 * c4;     // coeff of cos a0 in m0
    float k01 = c2 * s4;     // coeff of sin a0 sin a2 in m0 (subtracted)

    // m = (b, pi, pjj), pjj in [0,32) selects a pair of patches (pj=2*pjj, 2*pjj+1).
    // H=W=128, nh=nw=64.
    int b   = m >> 11;
    int rem = m & 2047;
    int pi  = rem >> 5;
    int pjj = rem & 31;

    const float* base = x + ((size_t)b << 14) + (pi << 8) + (pjj << 2);
    // row 2*pi   : [a0(p0), a1(p0), a0(p1), a1(p1)]
    // row 2*pi+1 : [a2(p0), a3(p0), a2(p1), a3(p1)]
    vf4 r0 = *reinterpret_cast<const vf4*>(base);
    vf4 r1 = *reinterpret_cast<const vf4*>(base + 128);

    // ---- patch 0 ----
    float sa0, ca0; __sincosf(r0.x, &sa0, &ca0);
    float sa1, ca1; __sincosf(r0.y, &sa1, &ca1);
    float sa2, ca2; __sincosf(r1.x, &sa2, &ca2);
    float ca3 = __cosf(r1.y);
    float u   = c1 * ca1 - s1 * sa1;          // cos(a1 + t1)
    vf4 o0;
    o0.x = k00 * ca0 - k01 * (sa0 * sa2);
    o0.y = u;
    o0.z = c0 * (ca0 * ca2);
    o0.w = c3 * (u * ca3);

    // ---- patch 1 ----
    float sb0, cb0; __sincosf(r0.z, &sb0, &cb0);
    float sb1, cb1; __sincosf(r0.w, &sb1, &cb1);
    float sb2, cb2; __sincosf(r1.z, &sb2, &cb2);
    float cb3 = __cosf(r1.w);
    float v   = c1 * cb1 - s1 * sb1;          // cos(a1 + t1)
    vf4 o1;
    o1.x = k00 * cb0 - k01 * (sb0 * sb2);
    o1.y = v;
    o1.z = c0 * (cb0 * cb2);
    o1.w = c3 * (v * cb3);

    // n0 = 2m, n1 = 2m+1 -> 8 contiguous output floats at out + 8m.
    vf4* dst = reinterpret_cast<vf4*>(out + ((size_t)m << 3));
    __builtin_nontemporal_store(o0, dst);
    __builtin_nontemporal_store(o1, dst + 1);
}

extern "C" void kernel_launch(void* const* d_in, const int* in_sizes, int n_in,
                              void* d_out, int out_size, void* d_ws, size_t ws_size,
                              hipStream_t stream) {
    const float* x  = (const float*)d_in[0];
    const float* tp = (const float*)d_in[1];
    float* out = (float*)d_out;

    int N = in_sizes[0] / 4;   // number of 2x2 patches = 524288
    int M = N >> 1;            // pairs of patches = 262144
    const int threads = 256;
    int blocks = (M + threads - 1) / threads;
    qfe_kernel<<<blocks, threads, 0, stream>>>(x, tp, out, M);
}